// Round 4
// baseline (197.457 us; speedup 1.0000x reference)
//
#include <hip/hip_runtime.h>
#include <hip/hip_fp16.h>
#include <math.h>

#define LEAKY 0.01f

__device__ inline float2 h2f(uint w) {
    __half2 h = *reinterpret_cast<__half2*>(&w);
    return __half22float2(h);
}

// ---------------------------------------------------------------------------
// Kernel 1: per-node projections, single z pass computing BOTH halves.
//   U[n][j] = sum_k z[n][k] * W1[k][j]    + b1[j]
//   V[n][j] = sum_k z[n][k] * W1[64+k][j]
// stored fp16 (64 B per row).
// ---------------------------------------------------------------------------
__global__ __launch_bounds__(256) void node_proj_uv(
    const float* __restrict__ z, const float* __restrict__ W1,
    const float* __restrict__ b1, __half* __restrict__ U, __half* __restrict__ V,
    int N)
{
    int n = blockIdx.x * blockDim.x + threadIdx.x;
    if (n >= N) return;

    const float4* zr = reinterpret_cast<const float4*>(z + (size_t)n * 64);

    float au[32], av[32];
    #pragma unroll
    for (int j = 0; j < 32; ++j) { au[j] = b1[j]; av[j] = 0.0f; }

    #pragma unroll 4
    for (int k4 = 0; k4 < 16; ++k4) {
        float4 a = zr[k4];
        const float* wu0 = W1 + (4 * k4 + 0) * 32;
        const float* wu1 = W1 + (4 * k4 + 1) * 32;
        const float* wu2 = W1 + (4 * k4 + 2) * 32;
        const float* wu3 = W1 + (4 * k4 + 3) * 32;
        const float* wv0 = wu0 + 64 * 32;
        const float* wv1 = wu1 + 64 * 32;
        const float* wv2 = wu2 + 64 * 32;
        const float* wv3 = wu3 + 64 * 32;
        #pragma unroll
        for (int j = 0; j < 32; ++j) {
            float tu = au[j];
            tu = fmaf(a.x, wu0[j], tu);
            tu = fmaf(a.y, wu1[j], tu);
            tu = fmaf(a.z, wu2[j], tu);
            tu = fmaf(a.w, wu3[j], tu);
            au[j] = tu;
            float tv = av[j];
            tv = fmaf(a.x, wv0[j], tv);
            tv = fmaf(a.y, wv1[j], tv);
            tv = fmaf(a.z, wv2[j], tv);
            tv = fmaf(a.w, wv3[j], tv);
            av[j] = tv;
        }
    }

    uint wu[16], wv[16];
    #pragma unroll
    for (int i = 0; i < 16; ++i) {
        __half2 hu = __floats2half2_rn(au[2 * i], au[2 * i + 1]);
        wu[i] = *reinterpret_cast<uint*>(&hu);
        __half2 hv = __floats2half2_rn(av[2 * i], av[2 * i + 1]);
        wv[i] = *reinterpret_cast<uint*>(&hv);
    }
    uint4* du = reinterpret_cast<uint4*>(U + (size_t)n * 32);
    du[0] = make_uint4(wu[0], wu[1], wu[2], wu[3]);
    du[1] = make_uint4(wu[4], wu[5], wu[6], wu[7]);
    du[2] = make_uint4(wu[8], wu[9], wu[10], wu[11]);
    du[3] = make_uint4(wu[12], wu[13], wu[14], wu[15]);
    uint4* dv = reinterpret_cast<uint4*>(V + (size_t)n * 32);
    dv[0] = make_uint4(wv[0], wv[1], wv[2], wv[3]);
    dv[1] = make_uint4(wv[4], wv[5], wv[6], wv[7]);
    dv[2] = make_uint4(wv[8], wv[9], wv[10], wv[11]);
    dv[3] = make_uint4(wv[12], wv[13], wv[14], wv[15]);
}

// ---------------------------------------------------------------------------
// Kernel 2: quad-cooperative edge decode. 4 lanes per edge; lane p loads one
// contiguous 16-B quarter of u[s] and v[d] -> wave coalescer merges the quad's
// 4 pieces into ONE 64-B request per row (vs 4 requests/row before).
// Partial dot reduced with 2x shfl_xor inside the quad.
// ---------------------------------------------------------------------------
__global__ __launch_bounds__(256) void edge_decode_quad(
    const int* __restrict__ idx,
    const __half* __restrict__ U, const __half* __restrict__ V,
    const float* __restrict__ W2, const float* __restrict__ b2,
    float* __restrict__ out, int E)
{
    int t = blockIdx.x * blockDim.x + threadIdx.x;
    int e = t >> 2;
    int p = t & 3;
    if (e >= E) return;
    int s = idx[e];
    int d = idx[E + e];

    uint4 uq = *reinterpret_cast<const uint4*>(U + (size_t)s * 32 + p * 8);
    uint4 vq = *reinterpret_cast<const uint4*>(V + (size_t)d * 32 + p * 8);
    float4 w2a = *reinterpret_cast<const float4*>(W2 + p * 8);
    float4 w2b = *reinterpret_cast<const float4*>(W2 + p * 8 + 4);

    float acc = 0.0f;
    {
        float2 uu, vv; float h0, h1;
        uu = h2f(uq.x); vv = h2f(vq.x);
        h0 = uu.x + vv.x; h1 = uu.y + vv.y;
        h0 = (h0 >= 0.0f) ? h0 : LEAKY * h0;
        h1 = (h1 >= 0.0f) ? h1 : LEAKY * h1;
        acc = fmaf(h0, w2a.x, acc); acc = fmaf(h1, w2a.y, acc);
        uu = h2f(uq.y); vv = h2f(vq.y);
        h0 = uu.x + vv.x; h1 = uu.y + vv.y;
        h0 = (h0 >= 0.0f) ? h0 : LEAKY * h0;
        h1 = (h1 >= 0.0f) ? h1 : LEAKY * h1;
        acc = fmaf(h0, w2a.z, acc); acc = fmaf(h1, w2a.w, acc);
        uu = h2f(uq.z); vv = h2f(vq.z);
        h0 = uu.x + vv.x; h1 = uu.y + vv.y;
        h0 = (h0 >= 0.0f) ? h0 : LEAKY * h0;
        h1 = (h1 >= 0.0f) ? h1 : LEAKY * h1;
        acc = fmaf(h0, w2b.x, acc); acc = fmaf(h1, w2b.y, acc);
        uu = h2f(uq.w); vv = h2f(vq.w);
        h0 = uu.x + vv.x; h1 = uu.y + vv.y;
        h0 = (h0 >= 0.0f) ? h0 : LEAKY * h0;
        h1 = (h1 >= 0.0f) ? h1 : LEAKY * h1;
        acc = fmaf(h0, w2b.z, acc); acc = fmaf(h1, w2b.w, acc);
    }

    // quad reduce (stays inside the 4-lane group)
    acc += __shfl_xor(acc, 1);
    acc += __shfl_xor(acc, 2);

    float r = tanhf(acc + b2[0]);  // computed on all lanes (uniform, no branch)
    if (p == 0) out[e] = r;
}

// ---------------------------------------------------------------------------
// Fallback if the workspace is too small for U/V.
// ---------------------------------------------------------------------------
__global__ __launch_bounds__(256) void edge_mlp_f32(
    const float* __restrict__ z, const int* __restrict__ idx,
    const float* __restrict__ W1, const float* __restrict__ b1,
    const float* __restrict__ W2, const float* __restrict__ b2,
    float* __restrict__ out, int E)
{
    int e = blockIdx.x * blockDim.x + threadIdx.x;
    if (e >= E) return;
    int s = idx[e];
    int d = idx[E + e];
    const float4* zs = reinterpret_cast<const float4*>(z + (size_t)s * 64);
    const float4* zd = reinterpret_cast<const float4*>(z + (size_t)d * 64);

    float h[32];
    #pragma unroll
    for (int j = 0; j < 32; ++j) h[j] = b1[j];

    #pragma unroll 4
    for (int k4 = 0; k4 < 16; ++k4) {
        float4 a = zs[k4];
        float4 b = zd[k4];
        const float* wa0 = W1 + (4 * k4 + 0) * 32;
        const float* wa1 = W1 + (4 * k4 + 1) * 32;
        const float* wa2 = W1 + (4 * k4 + 2) * 32;
        const float* wa3 = W1 + (4 * k4 + 3) * 32;
        const float* wb0 = W1 + (64 + 4 * k4 + 0) * 32;
        const float* wb1 = W1 + (64 + 4 * k4 + 1) * 32;
        const float* wb2 = W1 + (64 + 4 * k4 + 2) * 32;
        const float* wb3 = W1 + (64 + 4 * k4 + 3) * 32;
        #pragma unroll
        for (int j = 0; j < 32; ++j) {
            float acc = h[j];
            acc = fmaf(a.x, wa0[j], acc);
            acc = fmaf(a.y, wa1[j], acc);
            acc = fmaf(a.z, wa2[j], acc);
            acc = fmaf(a.w, wa3[j], acc);
            acc = fmaf(b.x, wb0[j], acc);
            acc = fmaf(b.y, wb1[j], acc);
            acc = fmaf(b.z, wb2[j], acc);
            acc = fmaf(b.w, wb3[j], acc);
            h[j] = acc;
        }
    }

    float acc = b2[0];
    #pragma unroll
    for (int j = 0; j < 32; ++j) {
        float hv = h[j];
        hv = (hv >= 0.0f) ? hv : LEAKY * hv;
        acc = fmaf(hv, W2[j], acc);
    }
    out[e] = tanhf(acc);
}

extern "C" void kernel_launch(void* const* d_in, const int* in_sizes, int n_in,
                              void* d_out, int out_size, void* d_ws, size_t ws_size,
                              hipStream_t stream) {
    const float* z  = (const float*)d_in[0];
    const int*   idx = (const int*)d_in[1];
    const float* W1 = (const float*)d_in[2];
    const float* b1 = (const float*)d_in[3];
    const float* W2 = (const float*)d_in[4];
    const float* b2 = (const float*)d_in[5];
    float* out = (float*)d_out;

    const int E = out_size;            // 3,200,000
    const int N = in_sizes[0] / 64;    // 100,000 nodes

    size_t need = (size_t)2 * N * 32 * sizeof(__half);  // 12.8 MB
    if (ws_size >= need) {
        __half* U = (__half*)d_ws;
        __half* V = U + (size_t)N * 32;
        const int threads = 256;
        node_proj_uv<<<(N + threads - 1) / threads, threads, 0, stream>>>(
            z, W1, b1, U, V, N);
        // 4 lanes per edge
        long long tot = 4LL * E;
        edge_decode_quad<<<(int)((tot + threads - 1) / threads), threads, 0, stream>>>(
            idx, U, V, W2, b2, out, E);
    } else {
        const int threads = 256;
        edge_mlp_f32<<<(E + threads - 1) / threads, threads, 0, stream>>>(
            z, idx, W1, b1, W2, b2, out, E);
    }
}

// Round 7
// 183.827 us; speedup vs baseline: 1.0741x; 1.0741x over previous
//
#include <hip/hip_runtime.h>
#include <hip/hip_fp16.h>
#include <math.h>

#define LEAKY 0.01f

__device__ inline float fast_tanh(float x) {
    // tanh(x) = 1 - 2/(exp(2x)+1); exp via v_exp_f32, div via v_rcp_f32.
    float e2 = __expf(2.0f * x);
    return 1.0f - 2.0f * __builtin_amdgcn_rcpf(e2 + 1.0f);
}

__device__ inline float2 h2f(uint w) {
    __half2 h = *reinterpret_cast<__half2*>(&w);
    return __half22float2(h);
}

// ---------------------------------------------------------------------------
// Kernel 1: per-node projections, 4 threads per node (g = t&3 owns output
// dims g*8..g*8+7 of both U and V). W1 staged in LDS. 400k threads.
//   U[n][j] = sum_k z[n][k] * W1[k][j]    + b1[j]
//   V[n][j] = sum_k z[n][k] * W1[64+k][j]
// ---------------------------------------------------------------------------
__global__ __launch_bounds__(256) void node_proj_g4(
    const float* __restrict__ z, const float* __restrict__ W1,
    const float* __restrict__ b1, __half* __restrict__ U, __half* __restrict__ V,
    int N)
{
    __shared__ float w1s[128 * 32];  // 16 KB

    // cooperative W1 stage (all threads, before any exit)
    {
        const float4* src = reinterpret_cast<const float4*>(W1);
        float4* dst = reinterpret_cast<float4*>(w1s);
        int tid = threadIdx.x;
        #pragma unroll
        for (int i = 0; i < 4; ++i) dst[tid + 256 * i] = src[tid + 256 * i];
    }
    __syncthreads();

    int t = blockIdx.x * blockDim.x + threadIdx.x;
    int n = t >> 2;
    int g = t & 3;
    if (n >= N) return;

    const float4* zr = reinterpret_cast<const float4*>(z + (size_t)n * 64);

    float au[8], av[8];
    #pragma unroll
    for (int j = 0; j < 8; ++j) { au[j] = b1[g * 8 + j]; av[j] = 0.0f; }

    #pragma unroll 4
    for (int k4 = 0; k4 < 16; ++k4) {
        float4 a = zr[k4];
        #pragma unroll
        for (int c = 0; c < 4; ++c) {
            int k = 4 * k4 + c;
            float zk = (c == 0) ? a.x : (c == 1) ? a.y : (c == 2) ? a.z : a.w;
            const float4* wu = reinterpret_cast<const float4*>(&w1s[k * 32 + g * 8]);
            const float4* wv = reinterpret_cast<const float4*>(&w1s[(64 + k) * 32 + g * 8]);
            float4 wu0 = wu[0], wu1 = wu[1];
            float4 wv0 = wv[0], wv1 = wv[1];
            au[0] = fmaf(zk, wu0.x, au[0]);
            au[1] = fmaf(zk, wu0.y, au[1]);
            au[2] = fmaf(zk, wu0.z, au[2]);
            au[3] = fmaf(zk, wu0.w, au[3]);
            au[4] = fmaf(zk, wu1.x, au[4]);
            au[5] = fmaf(zk, wu1.y, au[5]);
            au[6] = fmaf(zk, wu1.z, au[6]);
            au[7] = fmaf(zk, wu1.w, au[7]);
            av[0] = fmaf(zk, wv0.x, av[0]);
            av[1] = fmaf(zk, wv0.y, av[1]);
            av[2] = fmaf(zk, wv0.z, av[2]);
            av[3] = fmaf(zk, wv0.w, av[3]);
            av[4] = fmaf(zk, wv1.x, av[4]);
            av[5] = fmaf(zk, wv1.y, av[5]);
            av[6] = fmaf(zk, wv1.z, av[6]);
            av[7] = fmaf(zk, wv1.w, av[7]);
        }
    }

    uint wu[4], wv[4];
    #pragma unroll
    for (int i = 0; i < 4; ++i) {
        __half2 hu = __floats2half2_rn(au[2 * i], au[2 * i + 1]);
        wu[i] = *reinterpret_cast<uint*>(&hu);
        __half2 hv = __floats2half2_rn(av[2 * i], av[2 * i + 1]);
        wv[i] = *reinterpret_cast<uint*>(&hv);
    }
    // lane-consecutive 16-B chunks -> fully coalesced
    *reinterpret_cast<uint4*>(U + (size_t)n * 32 + g * 8) = make_uint4(wu[0], wu[1], wu[2], wu[3]);
    *reinterpret_cast<uint4*>(V + (size_t)n * 32 + g * 8) = make_uint4(wv[0], wv[1], wv[2], wv[3]);
}

// ---------------------------------------------------------------------------
// Kernel 2: quad-cooperative edge decode, 4 edges per quad.
// Lane p loads the p-th 16-B quarter of u[s]/v[d] for 4 edges (8 gathers in
// flight), fp32 add+LeakyReLU+dot, 2x shfl_xor quad reduce. Lane p finishes
// (tanh+store) edge e0+p -> one tanh per lane, coalesced store.
// ---------------------------------------------------------------------------
__device__ inline float edge_dot(uint4 uq, uint4 vq, float4 w2a, float4 w2b) {
    float acc = 0.0f;
    float2 uu, vv; float h0, h1;
    uu = h2f(uq.x); vv = h2f(vq.x);
    h0 = uu.x + vv.x; h1 = uu.y + vv.y;
    h0 = (h0 >= 0.0f) ? h0 : LEAKY * h0;
    h1 = (h1 >= 0.0f) ? h1 : LEAKY * h1;
    acc = fmaf(h0, w2a.x, acc); acc = fmaf(h1, w2a.y, acc);
    uu = h2f(uq.y); vv = h2f(vq.y);
    h0 = uu.x + vv.x; h1 = uu.y + vv.y;
    h0 = (h0 >= 0.0f) ? h0 : LEAKY * h0;
    h1 = (h1 >= 0.0f) ? h1 : LEAKY * h1;
    acc = fmaf(h0, w2a.z, acc); acc = fmaf(h1, w2a.w, acc);
    uu = h2f(uq.z); vv = h2f(vq.z);
    h0 = uu.x + vv.x; h1 = uu.y + vv.y;
    h0 = (h0 >= 0.0f) ? h0 : LEAKY * h0;
    h1 = (h1 >= 0.0f) ? h1 : LEAKY * h1;
    acc = fmaf(h0, w2b.x, acc); acc = fmaf(h1, w2b.y, acc);
    uu = h2f(uq.w); vv = h2f(vq.w);
    h0 = uu.x + vv.x; h1 = uu.y + vv.y;
    h0 = (h0 >= 0.0f) ? h0 : LEAKY * h0;
    h1 = (h1 >= 0.0f) ? h1 : LEAKY * h1;
    acc = fmaf(h0, w2b.z, acc); acc = fmaf(h1, w2b.w, acc);
    return acc;
}

__global__ __launch_bounds__(256) void edge_decode_q4(
    const int* __restrict__ idx,
    const __half* __restrict__ U, const __half* __restrict__ V,
    const float* __restrict__ W2, const float* __restrict__ b2,
    float* __restrict__ out, int E)
{
    int t = blockIdx.x * blockDim.x + threadIdx.x;
    int p = t & 3;
    int e0 = t & ~3;  // quad's first edge
    if (e0 >= E) return;
    int eN = E - 1;
    int ea = min(e0, eN), eb = min(e0 + 1, eN), ec = min(e0 + 2, eN), ed = min(e0 + 3, eN);

    int s0 = idx[ea], s1 = idx[eb], s2 = idx[ec], s3 = idx[ed];
    int d0 = idx[E + ea], d1 = idx[E + eb], d2 = idx[E + ec], d3 = idx[E + ed];

    const uint4* Up = reinterpret_cast<const uint4*>(U);
    const uint4* Vp = reinterpret_cast<const uint4*>(V);
    uint4 u0 = Up[(size_t)s0 * 4 + p];
    uint4 u1 = Up[(size_t)s1 * 4 + p];
    uint4 u2 = Up[(size_t)s2 * 4 + p];
    uint4 u3 = Up[(size_t)s3 * 4 + p];
    uint4 v0 = Vp[(size_t)d0 * 4 + p];
    uint4 v1 = Vp[(size_t)d1 * 4 + p];
    uint4 v2 = Vp[(size_t)d2 * 4 + p];
    uint4 v3 = Vp[(size_t)d3 * 4 + p];

    float4 w2a = *reinterpret_cast<const float4*>(W2 + p * 8);
    float4 w2b = *reinterpret_cast<const float4*>(W2 + p * 8 + 4);

    float a0 = edge_dot(u0, v0, w2a, w2b);
    float a1 = edge_dot(u1, v1, w2a, w2b);
    float a2 = edge_dot(u2, v2, w2a, w2b);
    float a3 = edge_dot(u3, v3, w2a, w2b);

    // quad reduce (xor 1, 2 stay inside the 4-lane group)
    a0 += __shfl_xor(a0, 1); a0 += __shfl_xor(a0, 2);
    a1 += __shfl_xor(a1, 1); a1 += __shfl_xor(a1, 2);
    a2 += __shfl_xor(a2, 1); a2 += __shfl_xor(a2, 2);
    a3 += __shfl_xor(a3, 1); a3 += __shfl_xor(a3, 2);

    // lane p finishes edge e0+p: one tanh per lane, coalesced store
    float r = (p == 0) ? a0 : (p == 1) ? a1 : (p == 2) ? a2 : a3;
    r = fast_tanh(r + b2[0]);
    int eo = e0 + p;
    if (eo < E) out[eo] = r;
}

// ---------------------------------------------------------------------------
// Fallback if the workspace is too small for U/V.
// ---------------------------------------------------------------------------
__global__ __launch_bounds__(256) void edge_mlp_f32(
    const float* __restrict__ z, const int* __restrict__ idx,
    const float* __restrict__ W1, const float* __restrict__ b1,
    const float* __restrict__ W2, const float* __restrict__ b2,
    float* __restrict__ out, int E)
{
    int e = blockIdx.x * blockDim.x + threadIdx.x;
    if (e >= E) return;
    int s = idx[e];
    int d = idx[E + e];
    const float4* zs = reinterpret_cast<const float4*>(z + (size_t)s * 64);
    const float4* zd = reinterpret_cast<const float4*>(z + (size_t)d * 64);

    float h[32];
    #pragma unroll
    for (int j = 0; j < 32; ++j) h[j] = b1[j];

    #pragma unroll 4
    for (int k4 = 0; k4 < 16; ++k4) {
        float4 a = zs[k4];
        float4 b = zd[k4];
        const float* wa0 = W1 + (4 * k4 + 0) * 32;
        const float* wa1 = W1 + (4 * k4 + 1) * 32;
        const float* wa2 = W1 + (4 * k4 + 2) * 32;
        const float* wa3 = W1 + (4 * k4 + 3) * 32;
        const float* wb0 = W1 + (64 + 4 * k4 + 0) * 32;
        const float* wb1 = W1 + (64 + 4 * k4 + 1) * 32;
        const float* wb2 = W1 + (64 + 4 * k4 + 2) * 32;
        const float* wb3 = W1 + (64 + 4 * k4 + 3) * 32;
        #pragma unroll
        for (int j = 0; j < 32; ++j) {
            float acc = h[j];
            acc = fmaf(a.x, wa0[j], acc);
            acc = fmaf(a.y, wa1[j], acc);
            acc = fmaf(a.z, wa2[j], acc);
            acc = fmaf(a.w, wa3[j], acc);
            acc = fmaf(b.x, wb0[j], acc);
            acc = fmaf(b.y, wb1[j], acc);
            acc = fmaf(b.z, wb2[j], acc);
            acc = fmaf(b.w, wb3[j], acc);
            h[j] = acc;
        }
    }

    float acc = b2[0];
    #pragma unroll
    for (int j = 0; j < 32; ++j) {
        float hv = h[j];
        hv = (hv >= 0.0f) ? hv : LEAKY * hv;
        acc = fmaf(hv, W2[j], acc);
    }
    out[e] = tanhf(acc);
}

extern "C" void kernel_launch(void* const* d_in, const int* in_sizes, int n_in,
                              void* d_out, int out_size, void* d_ws, size_t ws_size,
                              hipStream_t stream) {
    const float* z  = (const float*)d_in[0];
    const int*   idx = (const int*)d_in[1];
    const float* W1 = (const float*)d_in[2];
    const float* b1 = (const float*)d_in[3];
    const float* W2 = (const float*)d_in[4];
    const float* b2 = (const float*)d_in[5];
    float* out = (float*)d_out;

    const int E = out_size;            // 3,200,000
    const int N = in_sizes[0] / 64;    // 100,000 nodes

    size_t need = (size_t)2 * N * 32 * sizeof(__half);  // 12.8 MB
    if (ws_size >= need) {
        __half* U = (__half*)d_ws;
        __half* V = U + (size_t)N * 32;
        const int threads = 256;
        int nthread_np = 4 * N;
        node_proj_g4<<<(nthread_np + threads - 1) / threads, threads, 0, stream>>>(
            z, W1, b1, U, V, N);
        edge_decode_q4<<<(E + threads - 1) / threads, threads, 0, stream>>>(
            idx, U, V, W2, b2, out, E);
    } else {
        const int threads = 256;
        edge_mlp_f32<<<(E + threads - 1) / threads, threads, 0, stream>>>(
            z, idx, W1, b1, W2, b2, out, E);
    }
}